// Round 3
// baseline (834.691 us; speedup 1.0000x reference)
//
#include <hip/hip_runtime.h>
#include <math.h>

// ---------------- problem constants ----------------
#define TASKS 64
#define NB    4096
#define TDI   512     // token dim (K of GEMM1)
#define HDI   256     // hidden dim
#define VDI   484     // visual dim (padded to 512; col 484 = wc = W2^T.c fused dot column)

// ---------------- ws layout (bytes): plain linear bf16 arrays ----------------
#define WS_TF   ((size_t)0)                       // [4096][512] bf16
#define WS_W1H  ((size_t)4194304)                 // [64][256][512] bf16
#define WS_W1L  ((size_t)20971520)
#define WS_W2H  ((size_t)37748736)                // [64][512][256] bf16 (rows 484=wc, 485..511=0)
#define WS_W2L  ((size_t)54525952)
#define WS_CN   ((size_t)71303168)                // 64 f32 centroid norms
#define WS_BC   ((size_t)71303424)                // 64 f32 b2.c
#define WS_ACC  ((size_t)71303680)                // 64 f32 distance accumulators

// ---------------- LDS layout (bytes): 39424 total -> 2 blocks x 512thr / CU ----------------
#define LDS_HP 0          // 32768: H' [32 kgroups][64 m][8] bf16
#define LDS_B2 32768      // 512 f32: b2 (col 484 = bc, 485.. = 0)
#define LDS_R0 34816      // 512 f32: [8w][64m]
#define LDS_R1 36864      // 512 f32
#define LDS_MU 38912      // 64 f32
#define LDS_RS 39168      // 64 f32
#define SMEM_BYTES 39424

typedef __bf16 bf16x8 __attribute__((ext_vector_type(8)));
typedef float  f32x4  __attribute__((ext_vector_type(4)));

__device__ __forceinline__ unsigned short f2bf(float x) {   // RNE float->bf16
  unsigned u = __float_as_uint(x);
  u += 0x7fffu + ((u >> 16) & 1u);
  return (unsigned short)(u >> 16);
}
__device__ __forceinline__ float bf2f(unsigned short h) {
  return __uint_as_float(((unsigned)h) << 16);
}

#define MFMA16(a, b, c) __builtin_amdgcn_mfma_f32_16x16x32_bf16((a), (b), (c), 0, 0, 0)

// ================= prepass: fp32 -> linear bf16 (hi/lo split for weights) =================
// All parts coalesced on BOTH read and write (layouts are identity / near-identity).
extern "C" __global__ void prep_all(const float* __restrict__ t_feat,
                                    const float* __restrict__ W1,
                                    const float* __restrict__ W2,
                                    const float* __restrict__ b2,
                                    const float* __restrict__ cent,
                                    unsigned short* __restrict__ tf,
                                    unsigned short* __restrict__ w1h,
                                    unsigned short* __restrict__ w1l,
                                    unsigned short* __restrict__ w2h,
                                    unsigned short* __restrict__ w2l,
                                    float* __restrict__ cnorm,
                                    float* __restrict__ bc,
                                    float* __restrict__ accum) {
  const int bid = blockIdx.x, tid = threadIdx.x;
  __shared__ float redc[256], redb[256];
  if (bid < 2048) {                       // t_feat -> tf (identity layout)
    int p = bid * 256 + tid;              // float4 index, [0, 524288)
    float4 v = ((const float4*)t_feat)[p];
    ushort4 u; u.x = f2bf(v.x); u.y = f2bf(v.y); u.z = f2bf(v.z); u.w = f2bf(v.w);
    ((ushort4*)tf)[p] = u;
  } else if (bid < 10240) {               // W1 -> w1h/w1l (identity layout)
    int p = (bid - 2048) * 256 + tid;     // [0, 2097152)
    float4 v = ((const float4*)W1)[p];
    ushort4 uh, ul;
    uh.x = f2bf(v.x); ul.x = f2bf(v.x - bf2f(uh.x));
    uh.y = f2bf(v.y); ul.y = f2bf(v.y - bf2f(uh.y));
    uh.z = f2bf(v.z); ul.z = f2bf(v.z - bf2f(uh.z));
    uh.w = f2bf(v.w); ul.w = f2bf(v.w - bf2f(uh.w));
    ((ushort4*)w1h)[p] = uh;
    ((ushort4*)w1l)[p] = ul;
  } else if (bid < 17984) {               // W2 rows 0..483 -> padded [512] layout
    int p = (bid - 10240) * 256 + tid;    // [0, 1982464)
    int t = p / 30976;                    // 484*64 float4 per task
    int rem = p - t * 30976;
    int v4 = rem >> 6, h4 = rem & 63;
    float4 v = ((const float4*)W2)[p];
    ushort4 uh, ul;
    uh.x = f2bf(v.x); ul.x = f2bf(v.x - bf2f(uh.x));
    uh.y = f2bf(v.y); ul.y = f2bf(v.y - bf2f(uh.y));
    uh.z = f2bf(v.z); ul.z = f2bf(v.z - bf2f(uh.z));
    uh.w = f2bf(v.w); ul.w = f2bf(v.w - bf2f(uh.w));
    size_t o = ((size_t)t * 512 + v4) * 64 + h4;
    ((ushort4*)w2h)[o] = uh;
    ((ushort4*)w2l)[o] = ul;
  } else {                                // per-task: wc row, zero pad rows, cnorm, bc
    int t = bid - 17984;
    int h = tid;                          // 0..255
    float wcv = 0.f;
    for (int v = 0; v < VDI; ++v)
      wcv += W2[((size_t)t * VDI + v) * HDI + h] * cent[(size_t)t * VDI + v];
    unsigned short hi = f2bf(wcv), lo = f2bf(wcv - bf2f(hi));
    w2h[((size_t)t * 512 + 484) * HDI + h] = hi;
    w2l[((size_t)t * 512 + 484) * HDI + h] = lo;
    #pragma unroll
    for (int r = 485; r < 512; ++r) {
      w2h[((size_t)t * 512 + r) * HDI + h] = 0;
      w2l[((size_t)t * 512 + r) * HDI + h] = 0;
    }
    float c2 = 0.f, b2c = 0.f;
    for (int v = h; v < VDI; v += 256) {
      float c = cent[(size_t)t * VDI + v];
      c2 += c * c;
      b2c += b2[(size_t)t * VDI + v] * c;
    }
    redc[tid] = c2; redb[tid] = b2c;
    __syncthreads();
    if (tid < 64) {
      c2  = redc[tid] + redc[tid + 64] + redc[tid + 128] + redc[tid + 192];
      b2c = redb[tid] + redb[tid + 64] + redb[tid + 128] + redb[tid + 192];
      #pragma unroll
      for (int off = 32; off; off >>= 1) { c2 += __shfl_xor(c2, off); b2c += __shfl_xor(b2c, off); }
      if (tid == 0) { cnorm[t] = sqrtf(c2); bc[t] = b2c; accum[t] = 0.f; }
    }
  }
}

// ================= fused main kernel: 512 thr, 8 waves, 64 rows x 32 cols per wave =================
#define LOADA1(D, KS) do { int c_ = aBase + (KS) * 4;                          \
  D[0] = tfv[c_]; D[1] = tfv[c_ + 1024]; D[2] = tfv[c_ + 2048]; D[3] = tfv[c_ + 3072]; } while (0)

#define LOADB1(DH, DL, KS) do { int c_ = bBase + (KS) * 4;                     \
  DH[0] = w1hv[c_]; DH[1] = w1hv[c_ + 1024];                                   \
  DL[0] = w1lv[c_]; DL[1] = w1lv[c_ + 1024]; } while (0)

#define LOADA2(D, KS) do { int o_ = (((KS) * 4 + quad) * 64 + l15) * 16;       \
  D[0] = *(const bf16x8*)(smem + LDS_HP + o_);                                 \
  D[1] = *(const bf16x8*)(smem + LDS_HP + o_ + 256);                           \
  D[2] = *(const bf16x8*)(smem + LDS_HP + o_ + 512);                           \
  D[3] = *(const bf16x8*)(smem + LDS_HP + o_ + 768); } while (0)

#define LOADB2(DH, DL, KS) do { int c_ = cBase + (KS) * 4;                     \
  DH[0] = w2hv[c_]; DH[1] = w2hv[c_ + 512];                                    \
  DL[0] = w2lv[c_]; DL[1] = w2lv[c_ + 512]; } while (0)

#define STEP(ACC, A, BH, BL) do {                                              \
  _Pragma("unroll") for (int ct_ = 0; ct_ < 2; ++ct_) {                        \
    _Pragma("unroll") for (int rt_ = 0; rt_ < 4; ++rt_) {                      \
      ACC[rt_][ct_] = MFMA16(A[rt_], BH[ct_], ACC[rt_][ct_]);                  \
      ACC[rt_][ct_] = MFMA16(A[rt_], BL[ct_], ACC[rt_][ct_]);                  \
    } } } while (0)

extern "C" __global__ void __launch_bounds__(512, 4)
router_main(const bf16x8* __restrict__ tfv,
            const bf16x8* __restrict__ w1hv,
            const bf16x8* __restrict__ w1lv,
            const bf16x8* __restrict__ w2hv,
            const bf16x8* __restrict__ w2lv,
            const float* __restrict__ b1,
            const float* __restrict__ gamma,
            const float* __restrict__ beta,
            const float* __restrict__ b2,
            const float* __restrict__ bc,
            const float* __restrict__ cnorm,
            float* __restrict__ accum) {
  __shared__ __align__(16) char smem[SMEM_BYTES];

  const int tid = threadIdx.x;
  const int bx  = blockIdx.x;
  // XCD swizzle: each XCD (bx&7) works one task at a time -> weights L2-resident.
  const int t  = ((bx & 7) << 3) | (bx >> 9);
  const int rb = (bx >> 3) & 63;

  const int lane = tid & 63;
  const int w    = tid >> 6;       // wave id 0..7
  const int quad = lane >> 4;
  const int l15  = lane & 15;

  // ---- preload b2 (+bc at col 484) into LDS; LN vectors into registers ----
  {
    float* b2s = (float*)(smem + LDS_B2);
    float v = 0.f;
    if (tid < VDI) v = b2[(size_t)t * VDI + tid];
    else if (tid == VDI) v = bc[t];
    b2s[tid] = v;
  }
  float b1v[2], gv[2], bev[2];
  #pragma unroll
  for (int ct = 0; ct < 2; ++ct) {
    int col = w * 32 + ct * 16 + l15;
    b1v[ct] = b1[t * HDI + col];
    gv[ct]  = gamma[t * HDI + col];
    bev[ct] = beta[t * HDI + col];
  }

  f32x4 zero4 = {0.f, 0.f, 0.f, 0.f};
  f32x4 acc[4][2];
  #pragma unroll
  for (int rt = 0; rt < 4; ++rt) { acc[rt][0] = zero4; acc[rt][1] = zero4; }

  bf16x8 a0[4], a1[4], bh0[2], bh1[2], bl0[2], bl1[2];

  // ================= Phase 1: GEMM1 (K=512), barrier-free, frags direct from L2 =================
  {
    // linear bf16 [row][k]: frag chunk = row*64 + ks*4 + quad  (bf16x8 units)
    const int aBase = (rb * 64 + l15) * 64 + quad;            // rt stride 1024
    const int bBase = (t * 256 + w * 32 + l15) * 64 + quad;   // ct stride 1024
    LOADA1(a0, 0); LOADB1(bh0, bl0, 0);
    LOADA1(a1, 1); LOADB1(bh1, bl1, 1);
    #pragma unroll 1
    for (int ks = 0; ks < 14; ks += 2) {
      STEP(acc, a0, bh0, bl0);
      LOADA1(a0, ks + 2); LOADB1(bh0, bl0, ks + 2);
      STEP(acc, a1, bh1, bl1);
      LOADA1(a1, ks + 3); LOADB1(bh1, bl1, ks + 3);
    }
    STEP(acc, a0, bh0, bl0);
    STEP(acc, a1, bh1, bl1);
  }

  // ================= Phase 2: +b1, LayerNorm, exact GELU -> H' (bf16) in LDS =================
  {
    float* red0 = (float*)(smem + LDS_R0);
    float* red1 = (float*)(smem + LDS_R1);
    #pragma unroll
    for (int rt = 0; rt < 4; ++rt)
      #pragma unroll
      for (int r = 0; r < 4; ++r) {
        float sv = 0.f, qv = 0.f;
        #pragma unroll
        for (int ct = 0; ct < 2; ++ct) {
          float v = acc[rt][ct][r] + b1v[ct];
          acc[rt][ct][r] = v;
          sv += v; qv += v * v;
        }
        sv += __shfl_xor(sv, 1); qv += __shfl_xor(qv, 1);
        sv += __shfl_xor(sv, 2); qv += __shfl_xor(qv, 2);
        sv += __shfl_xor(sv, 4); qv += __shfl_xor(qv, 4);
        sv += __shfl_xor(sv, 8); qv += __shfl_xor(qv, 8);
        if (l15 == 0) {
          int m = rt * 16 + quad * 4 + r;
          red0[w * 64 + m] = sv;
          red1[w * 64 + m] = qv;
        }
      }
    __syncthreads();
    if (tid < 64) {
      float s = 0.f, q = 0.f;
      #pragma unroll
      for (int ww = 0; ww < 8; ++ww) { s += red0[ww * 64 + tid]; q += red1[ww * 64 + tid]; }
      float mu = s * (1.f / HDI);
      float var = q * (1.f / HDI) - mu * mu;
      ((float*)(smem + LDS_MU))[tid] = mu;
      ((float*)(smem + LDS_RS))[tid] = rsqrtf(var + 1e-5f);
    }
    __syncthreads();
    const float* mus = (const float*)(smem + LDS_MU);
    const float* rss = (const float*)(smem + LDS_RS);
    #pragma unroll
    for (int rt = 0; rt < 4; ++rt)
      #pragma unroll
      for (int ct = 0; ct < 2; ++ct)
        #pragma unroll
        for (int r = 0; r < 4; ++r) {
          int col = w * 32 + ct * 16 + l15;
          int m   = rt * 16 + quad * 4 + r;
          float x = (acc[rt][ct][r] - mus[m]) * rss[m];
          x = x * gv[ct] + bev[ct];
          float g = 0.5f * x * (1.f + erff(x * 0.70710678118654752f));
          *(unsigned short*)(smem + LDS_HP + (size_t)((col >> 3) * 64 + m) * 16 + (col & 7) * 2) = f2bf(g);
        }
    __syncthreads();
  }

  // ================= Phase 3: GEMM2 (2 N-passes of 256, incl. fused wc dot column) =================
  {
    const float* b2s = (const float*)(smem + LDS_B2);
    float* red0 = (float*)(smem + LDS_R0);
    float* red1 = (float*)(smem + LDS_R1);

    #pragma unroll 1
    for (int pass = 0; pass < 2; ++pass) {
      const int cBase = (t * 512 + pass * 256 + w * 32 + l15) * 32 + quad;  // ct stride 512
      f32x4 acc2[4][2];
      #pragma unroll
      for (int rt = 0; rt < 4; ++rt) { acc2[rt][0] = zero4; acc2[rt][1] = zero4; }

      LOADA2(a0, 0); LOADB2(bh0, bl0, 0);
      LOADA2(a1, 1); LOADB2(bh1, bl1, 1);
      #pragma unroll 1
      for (int ks = 0; ks < 6; ks += 2) {
        STEP(acc2, a0, bh0, bl0);
        LOADA2(a0, ks + 2); LOADB2(bh0, bl0, ks + 2);
        STEP(acc2, a1, bh1, bl1);
        LOADA2(a1, ks + 3); LOADB2(bh1, bl1, ks + 3);
      }
      STEP(acc2, a0, bh0, bl0);
      STEP(acc2, a1, bh1, bl1);

      // epilogue: per-row |v|^2 (cols<484) and dot (col 484 = wc column + bc)
      #pragma unroll
      for (int rt = 0; rt < 4; ++rt)
        #pragma unroll
        for (int r = 0; r < 4; ++r) {
          float ssq = 0.f, dtv = 0.f;
          #pragma unroll
          for (int ct = 0; ct < 2; ++ct) {
            int vcol = pass * 256 + w * 32 + ct * 16 + l15;
            float val = acc2[rt][ct][r] + b2s[vcol];
            ssq += (vcol < VDI) ? val * val : 0.f;
            dtv += (vcol == VDI) ? val : 0.f;
          }
          ssq += __shfl_xor(ssq, 1); dtv += __shfl_xor(dtv, 1);
          ssq += __shfl_xor(ssq, 2); dtv += __shfl_xor(dtv, 2);
          ssq += __shfl_xor(ssq, 4); dtv += __shfl_xor(dtv, 4);
          ssq += __shfl_xor(ssq, 8); dtv += __shfl_xor(dtv, 8);
          if (l15 == 0) {
            int m = rt * 16 + quad * 4 + r;
            if (pass == 0) {
              red0[w * 64 + m] = ssq;
            } else {
              red0[w * 64 + m] += ssq;
              red1[w * 64 + m] = dtv;
            }
          }
        }
    }

    __syncthreads();
    if (tid < 64) {
      float ss = 0.f, dot = 0.f;
      #pragma unroll
      for (int ww = 0; ww < 8; ++ww) { ss += red0[ww * 64 + tid]; dot += red1[ww * 64 + tid]; }
      float cn = fmaxf(cnorm[t], 1e-8f);
      float vn = fmaxf(sqrtf(ss), 1e-8f);
      float part = 1.0f - dot / (vn * cn);
      part += __shfl_down(part, 32);
      part += __shfl_down(part, 16);
      part += __shfl_down(part, 8);
      part += __shfl_down(part, 4);
      part += __shfl_down(part, 2);
      part += __shfl_down(part, 1);
      if (tid == 0) atomicAdd(accum + t, part);
    }
  }
}

// ================= finalize: mean, argmin =================
extern "C" __global__ void finalize_k(const float* __restrict__ accum, float* __restrict__ out) {
  int t = threadIdx.x;                               // <<<1, 64>>>
  float d = accum[t] * (1.0f / (float)NB);
  out[t] = d;
  float bd = d; int bi = t;
  #pragma unroll
  for (int off = 32; off; off >>= 1) {
    float od = __shfl_xor(bd, off);
    int   oi = __shfl_xor(bi, off);
    if (od < bd || (od == bd && oi < bi)) { bd = od; bi = oi; }   // first-min tie-break
  }
  if (t == 0) out[64] = (float)bi;
}

extern "C" void kernel_launch(void* const* d_in, const int* in_sizes, int n_in,
                              void* d_out, int out_size, void* d_ws, size_t ws_size,
                              hipStream_t stream) {
  const float* t_feat = (const float*)d_in[0];
  const float* W1     = (const float*)d_in[1];
  const float* b1     = (const float*)d_in[2];
  const float* gamma  = (const float*)d_in[3];
  const float* beta   = (const float*)d_in[4];
  const float* W2     = (const float*)d_in[5];
  const float* b2     = (const float*)d_in[6];
  const float* cent   = (const float*)d_in[7];

  char* ws = (char*)d_ws;   // requires ws_size >= ~68 MiB
  unsigned short* tf  = (unsigned short*)(ws + WS_TF);
  unsigned short* w1h = (unsigned short*)(ws + WS_W1H);
  unsigned short* w1l = (unsigned short*)(ws + WS_W1L);
  unsigned short* w2h = (unsigned short*)(ws + WS_W2H);
  unsigned short* w2l = (unsigned short*)(ws + WS_W2L);
  float* cnorm = (float*)(ws + WS_CN);
  float* bc    = (float*)(ws + WS_BC);
  float* accum = (float*)(ws + WS_ACC);
  float* out = (float*)d_out;

  prep_all<<<18048, 256, 0, stream>>>(t_feat, W1, W2, b2, cent,
                                      tf, w1h, w1l, w2h, w2l, cnorm, bc, accum);
  router_main<<<4096, 512, 0, stream>>>((const bf16x8*)tf, (const bf16x8*)w1h, (const bf16x8*)w1l,
                                        (const bf16x8*)w2h, (const bf16x8*)w2l,
                                        b1, gamma, beta, b2, bc, cnorm, accum);
  finalize_k<<<1, 64, 0, stream>>>(accum, out);
}

// Round 4
// 496.837 us; speedup vs baseline: 1.6800x; 1.6800x over previous
//
#include <hip/hip_runtime.h>
#include <math.h>

// ---------------- problem constants ----------------
#define TASKS 64
#define NB    4096
#define TDI   512     // token dim (K of GEMM1)
#define HDI   256     // hidden dim
#define VDI   484     // visual dim (padded to 512; row 484 = wc = W2^T.c fused dot column)

// ---------------- ws layout (bytes): plain linear fp16 arrays ----------------
#define WS_TF   ((size_t)0)                       // [4096][512] f16      (4 MB)
#define WS_W1   ((size_t)4194304)                 // [64][256][512] f16   (16 MB)
#define WS_W2   ((size_t)20971520)                // [64][512][256] f16   (16 MB; rows 484=wc, 485..511=0)
#define WS_CN   ((size_t)37748736)                // 64 f32 centroid norms
#define WS_BC   ((size_t)37748992)                // 64 f32 b2.c
#define WS_ACC  ((size_t)37749248)                // 64 f32 distance accumulators

// ---------------- LDS layout (bytes): 37376 total ----------------
#define LDS_HP 0          // 32768: H' [32 kgroups][64 m][8] f16
#define LDS_B2 32768      // 512 f32: b2 (col 484 = b2.c, 485.. = 0)
#define LDS_R0 34816      // 256 f32: [4w][64m]
#define LDS_R1 35840      // 256 f32
#define LDS_MU 36864      // 64 f32
#define LDS_RS 37120      // 64 f32
#define SMEM_BYTES 37376

typedef _Float16 half8 __attribute__((ext_vector_type(8)));
typedef float    f32x4 __attribute__((ext_vector_type(4)));

#define MFMA16(a, b, c) __builtin_amdgcn_mfma_f32_16x16x32_f16((a), (b), (c), 0, 0, 0)

// ================= prepass: fp32 -> linear fp16, all coalesced =================
extern "C" __global__ void prep_all(const float* __restrict__ t_feat,
                                    const float* __restrict__ W1,
                                    const float* __restrict__ W2,
                                    const float* __restrict__ b2,
                                    const float* __restrict__ cent,
                                    _Float16* __restrict__ tf,
                                    _Float16* __restrict__ w1,
                                    _Float16* __restrict__ w2,
                                    float* __restrict__ cnorm,
                                    float* __restrict__ bc,
                                    float* __restrict__ accum) {
  const int bid = blockIdx.x, tid = threadIdx.x;
  __shared__ float redc[256], redb[256];
  if (bid < 2048) {                       // t_feat -> tf (identity layout)
    int p = bid * 256 + tid;              // float4 index, [0, 524288)
    float4 v = ((const float4*)t_feat)[p];
    _Float16 h4[4] = {(_Float16)v.x, (_Float16)v.y, (_Float16)v.z, (_Float16)v.w};
    *(ushort4*)(tf + (size_t)p * 4) = *(const ushort4*)h4;
  } else if (bid < 10240) {               // W1 -> w1 (identity layout)
    int p = (bid - 2048) * 256 + tid;     // [0, 2097152)
    float4 v = ((const float4*)W1)[p];
    _Float16 h4[4] = {(_Float16)v.x, (_Float16)v.y, (_Float16)v.z, (_Float16)v.w};
    *(ushort4*)(w1 + (size_t)p * 4) = *(const ushort4*)h4;
  } else if (bid < 17984) {               // W2 rows 0..483 -> padded [512] layout
    int p = (bid - 10240) * 256 + tid;    // [0, 1982464)
    int t = p / 30976;                    // 484*64 float4 per task
    int rem = p - t * 30976;
    int v4 = rem >> 6, h4i = rem & 63;
    float4 v = ((const float4*)W2)[p];
    _Float16 h4[4] = {(_Float16)v.x, (_Float16)v.y, (_Float16)v.z, (_Float16)v.w};
    size_t o = ((size_t)t * 512 + v4) * 64 + h4i;
    *(ushort4*)(w2 + o * 4) = *(const ushort4*)h4;
  } else {                                // per-task: wc row, zero pad rows, cnorm, b2.c
    int t = bid - 17984;
    int h = tid;                          // 0..255
    float wcv = 0.f;
    for (int v = 0; v < VDI; ++v)
      wcv += W2[((size_t)t * VDI + v) * HDI + h] * cent[(size_t)t * VDI + v];
    w2[((size_t)t * 512 + 484) * HDI + h] = (_Float16)wcv;
    #pragma unroll
    for (int r = 485; r < 512; ++r)
      w2[((size_t)t * 512 + r) * HDI + h] = (_Float16)0.f;
    float c2 = 0.f, b2c = 0.f;
    for (int v = h; v < VDI; v += 256) {
      float c = cent[(size_t)t * VDI + v];
      c2 += c * c;
      b2c += b2[(size_t)t * VDI + v] * c;
    }
    redc[tid] = c2; redb[tid] = b2c;
    __syncthreads();
    if (tid < 64) {
      c2  = redc[tid] + redc[tid + 64] + redc[tid + 128] + redc[tid + 192];
      b2c = redb[tid] + redb[tid + 64] + redb[tid + 128] + redb[tid + 192];
      #pragma unroll
      for (int off = 32; off; off >>= 1) { c2 += __shfl_xor(c2, off); b2c += __shfl_xor(b2c, off); }
      if (tid == 0) { cnorm[t] = sqrtf(c2); bc[t] = b2c; accum[t] = 0.f; }
    }
  }
}

// ================= fused main kernel: 256 thr, 4 waves, 64 rows x 64 cols per wave =================
#define LOADA1(D, KS) do { int c_ = aBase + (KS) * 4;                          \
  D[0] = tfv[c_]; D[1] = tfv[c_ + 1024]; D[2] = tfv[c_ + 2048]; D[3] = tfv[c_ + 3072]; } while (0)

#define LOADB1(D, KS) do { int c_ = bBase + (KS) * 4;                          \
  D[0] = w1v[c_]; D[1] = w1v[c_ + 1024]; D[2] = w1v[c_ + 2048]; D[3] = w1v[c_ + 3072]; } while (0)

#define LOADA2(D, KS) do { int o_ = (((KS) * 4 + quad) * 64 + l15) * 16;       \
  D[0] = *(const half8*)(smem + LDS_HP + o_);                                  \
  D[1] = *(const half8*)(smem + LDS_HP + o_ + 256);                            \
  D[2] = *(const half8*)(smem + LDS_HP + o_ + 512);                            \
  D[3] = *(const half8*)(smem + LDS_HP + o_ + 768); } while (0)

#define LOADB2(D, KS) do { int c_ = cBase + (KS) * 4;                          \
  D[0] = w2v[c_]; D[1] = w2v[c_ + 512]; D[2] = w2v[c_ + 1024]; D[3] = w2v[c_ + 1536]; } while (0)

#define STEP(ACC, A, B) do {                                                   \
  _Pragma("unroll") for (int ct_ = 0; ct_ < 4; ++ct_) {                        \
    _Pragma("unroll") for (int rt_ = 0; rt_ < 4; ++rt_) {                      \
      ACC[rt_][ct_] = MFMA16(A[rt_], B[ct_], ACC[rt_][ct_]);                   \
    } } } while (0)

extern "C" __global__ void __launch_bounds__(256, 3)
router_main(const half8* __restrict__ tfv,
            const half8* __restrict__ w1v,
            const half8* __restrict__ w2v,
            const float* __restrict__ b1,
            const float* __restrict__ gamma,
            const float* __restrict__ beta,
            const float* __restrict__ b2,
            const float* __restrict__ bc,
            const float* __restrict__ cnorm,
            float* __restrict__ accum) {
  __shared__ __align__(16) char smem[SMEM_BYTES];

  const int tid = threadIdx.x;
  const int bx  = blockIdx.x;
  // XCD swizzle: each XCD (bx&7) works one task at a time -> 0.5MB task weights stay L2-resident.
  const int t  = ((bx & 7) << 3) | (bx >> 9);
  const int rb = (bx >> 3) & 63;

  const int lane = tid & 63;
  const int w    = tid >> 6;       // wave id 0..3
  const int quad = lane >> 4;
  const int l15  = lane & 15;

  // ---- preload b2 (+b2.c at col 484) into LDS; LN vectors into registers ----
  {
    float* b2s = (float*)(smem + LDS_B2);
    int i0 = tid;
    b2s[i0] = (i0 < VDI) ? b2[(size_t)t * VDI + i0] : 0.f;
    int i1 = tid + 256;
    float v = 0.f;
    if (i1 < VDI) v = b2[(size_t)t * VDI + i1];
    else if (i1 == VDI) v = bc[t];
    b2s[i1] = v;
  }
  float b1v[4], gv[4], bev[4];
  #pragma unroll
  for (int ct = 0; ct < 4; ++ct) {
    int col = w * 64 + ct * 16 + l15;
    b1v[ct] = b1[t * HDI + col];
    gv[ct]  = gamma[t * HDI + col];
    bev[ct] = beta[t * HDI + col];
  }

  f32x4 zero4 = {0.f, 0.f, 0.f, 0.f};
  f32x4 acc[4][4];
  #pragma unroll
  for (int rt = 0; rt < 4; ++rt)
    #pragma unroll
    for (int ct = 0; ct < 4; ++ct) acc[rt][ct] = zero4;

  half8 a0[4], a1[4], b0[4], b1f[4];

  // ================= Phase 1: GEMM1 (K=512), barrier-free, frags direct from L2 =================
  {
    // linear f16 [row][k]: frag chunk = row*64 + ks*4 + quad  (half8 units)
    const int aBase = (rb * 64 + l15) * 64 + quad;            // rt stride 1024
    const int bBase = (t * 256 + w * 64 + l15) * 64 + quad;   // ct stride 1024
    LOADA1(a0, 0); LOADB1(b0, 0);
    LOADA1(a1, 1); LOADB1(b1f, 1);
    #pragma unroll 1
    for (int ks = 0; ks < 14; ks += 2) {
      STEP(acc, a0, b0);
      LOADA1(a0, ks + 2); LOADB1(b0, ks + 2);
      STEP(acc, a1, b1f);
      LOADA1(a1, ks + 3); LOADB1(b1f, ks + 3);
    }
    STEP(acc, a0, b0);
    STEP(acc, a1, b1f);
  }

  // ================= Phase 2: +b1, LayerNorm, exact GELU -> H' (f16) in LDS =================
  {
    float* red0 = (float*)(smem + LDS_R0);
    float* red1 = (float*)(smem + LDS_R1);
    #pragma unroll
    for (int rt = 0; rt < 4; ++rt)
      #pragma unroll
      for (int r = 0; r < 4; ++r) {
        float sv = 0.f, qv = 0.f;
        #pragma unroll
        for (int ct = 0; ct < 4; ++ct) {
          float v = acc[rt][ct][r] + b1v[ct];
          acc[rt][ct][r] = v;
          sv += v; qv += v * v;
        }
        sv += __shfl_xor(sv, 1); qv += __shfl_xor(qv, 1);
        sv += __shfl_xor(sv, 2); qv += __shfl_xor(qv, 2);
        sv += __shfl_xor(sv, 4); qv += __shfl_xor(qv, 4);
        sv += __shfl_xor(sv, 8); qv += __shfl_xor(qv, 8);
        if (l15 == 0) {
          int m = rt * 16 + quad * 4 + r;
          red0[w * 64 + m] = sv;
          red1[w * 64 + m] = qv;
        }
      }
    __syncthreads();
    if (tid < 64) {
      float s = red0[tid] + red0[64 + tid] + red0[128 + tid] + red0[192 + tid];
      float q = red1[tid] + red1[64 + tid] + red1[128 + tid] + red1[192 + tid];
      float mu = s * (1.f / HDI);
      float var = q * (1.f / HDI) - mu * mu;
      ((float*)(smem + LDS_MU))[tid] = mu;
      ((float*)(smem + LDS_RS))[tid] = rsqrtf(var + 1e-5f);
    }
    __syncthreads();
    const float* mus = (const float*)(smem + LDS_MU);
    const float* rss = (const float*)(smem + LDS_RS);
    #pragma unroll
    for (int rt = 0; rt < 4; ++rt)
      #pragma unroll
      for (int ct = 0; ct < 4; ++ct)
        #pragma unroll
        for (int r = 0; r < 4; ++r) {
          int col = w * 64 + ct * 16 + l15;
          int m   = rt * 16 + quad * 4 + r;
          float x = (acc[rt][ct][r] - mus[m]) * rss[m];
          x = x * gv[ct] + bev[ct];
          float g = 0.5f * x * (1.f + erff(x * 0.70710678118654752f));
          *(_Float16*)(smem + LDS_HP + (size_t)((col >> 3) * 64 + m) * 16 + (col & 7) * 2) = (_Float16)g;
        }
    __syncthreads();
  }

  // ================= Phase 3: GEMM2 (2 N-passes of 256, incl. fused wc dot column) =================
  {
    const float* b2s = (const float*)(smem + LDS_B2);
    float* red0 = (float*)(smem + LDS_R0);
    float* red1 = (float*)(smem + LDS_R1);

    #pragma unroll 1
    for (int pass = 0; pass < 2; ++pass) {
      const int cBase = (t * 512 + pass * 256 + w * 64 + l15) * 32 + quad;  // ct stride 512
      f32x4 acc2[4][4];
      #pragma unroll
      for (int rt = 0; rt < 4; ++rt)
        #pragma unroll
        for (int ct = 0; ct < 4; ++ct) acc2[rt][ct] = zero4;

      LOADA2(a0, 0); LOADB2(b0, 0);
      LOADA2(a1, 1); LOADB2(b1f, 1);
      #pragma unroll 1
      for (int ks = 0; ks < 6; ks += 2) {
        STEP(acc2, a0, b0);
        LOADA2(a0, ks + 2); LOADB2(b0, ks + 2);
        STEP(acc2, a1, b1f);
        LOADA2(a1, ks + 3); LOADB2(b1f, ks + 3);
      }
      STEP(acc2, a0, b0);
      STEP(acc2, a1, b1f);

      // epilogue: per-row |v|^2 (cols<484) and dot (col 484 = wc column + b2.c)
      #pragma unroll
      for (int rt = 0; rt < 4; ++rt)
        #pragma unroll
        for (int r = 0; r < 4; ++r) {
          float ssq = 0.f, dtv = 0.f;
          #pragma unroll
          for (int ct = 0; ct < 4; ++ct) {
            int vcol = pass * 256 + w * 64 + ct * 16 + l15;
            float val = acc2[rt][ct][r] + b2s[vcol];
            ssq += (vcol < VDI) ? val * val : 0.f;
            dtv += (vcol == VDI) ? val : 0.f;
          }
          ssq += __shfl_xor(ssq, 1); dtv += __shfl_xor(dtv, 1);
          ssq += __shfl_xor(ssq, 2); dtv += __shfl_xor(dtv, 2);
          ssq += __shfl_xor(ssq, 4); dtv += __shfl_xor(dtv, 4);
          ssq += __shfl_xor(ssq, 8); dtv += __shfl_xor(dtv, 8);
          if (l15 == 0) {
            int m = rt * 16 + quad * 4 + r;
            if (pass == 0) {
              red0[w * 64 + m] = ssq;
            } else {
              red0[w * 64 + m] += ssq;
              red1[w * 64 + m] = dtv;
            }
          }
        }
    }

    __syncthreads();
    if (tid < 64) {
      float ss = red0[tid] + red0[64 + tid] + red0[128 + tid] + red0[192 + tid];
      float dot = red1[tid] + red1[64 + tid] + red1[128 + tid] + red1[192 + tid];
      float cn = fmaxf(cnorm[t], 1e-8f);
      float vn = fmaxf(sqrtf(ss), 1e-8f);
      float part = 1.0f - dot / (vn * cn);
      part += __shfl_down(part, 32);
      part += __shfl_down(part, 16);
      part += __shfl_down(part, 8);
      part += __shfl_down(part, 4);
      part += __shfl_down(part, 2);
      part += __shfl_down(part, 1);
      if (tid == 0) atomicAdd(accum + t, part);
    }
  }
}

// ================= finalize: mean, argmin =================
extern "C" __global__ void finalize_k(const float* __restrict__ accum, float* __restrict__ out) {
  int t = threadIdx.x;                               // <<<1, 64>>>
  float d = accum[t] * (1.0f / (float)NB);
  out[t] = d;
  float bd = d; int bi = t;
  #pragma unroll
  for (int off = 32; off; off >>= 1) {
    float od = __shfl_xor(bd, off);
    int   oi = __shfl_xor(bi, off);
    if (od < bd || (od == bd && oi < bi)) { bd = od; bi = oi; }   // first-min tie-break
  }
  if (t == 0) out[64] = (float)bi;
}

extern "C" void kernel_launch(void* const* d_in, const int* in_sizes, int n_in,
                              void* d_out, int out_size, void* d_ws, size_t ws_size,
                              hipStream_t stream) {
  const float* t_feat = (const float*)d_in[0];
  const float* W1     = (const float*)d_in[1];
  const float* b1     = (const float*)d_in[2];
  const float* gamma  = (const float*)d_in[3];
  const float* beta   = (const float*)d_in[4];
  const float* W2     = (const float*)d_in[5];
  const float* b2     = (const float*)d_in[6];
  const float* cent   = (const float*)d_in[7];

  char* ws = (char*)d_ws;   // requires ws_size >= ~38 MiB
  _Float16* tf = (_Float16*)(ws + WS_TF);
  _Float16* w1 = (_Float16*)(ws + WS_W1);
  _Float16* w2 = (_Float16*)(ws + WS_W2);
  float* cnorm = (float*)(ws + WS_CN);
  float* bc    = (float*)(ws + WS_BC);
  float* accum = (float*)(ws + WS_ACC);
  float* out = (float*)d_out;

  prep_all<<<18048, 256, 0, stream>>>(t_feat, W1, W2, b2, cent,
                                      tf, w1, w2, cnorm, bc, accum);
  router_main<<<4096, 256, 0, stream>>>((const half8*)tf, (const half8*)w1, (const half8*)w2,
                                        b1, gamma, beta, b2, bc, cnorm, accum);
  finalize_k<<<1, 64, 0, stream>>>(accum, out);
}